// Round 1
// baseline (3447.575 us; speedup 1.0000x reference)
//
#include <hip/hip_runtime.h>

// DFPS: density-weighted Manhattan furthest point sampling.
// points:   [B, N, 3] f32
// features: [B, C, N] f32 (unused)
// npoint:   int scalar (device, d_in[2])
// out:      [B, npoint] int32 indices

#define DENS_BLOCK 256
#define FPS_THREADS 512
#define FPS_P 16   // points per thread; FPS_THREADS * FPS_P must equal N (8192)

__global__ void dfps_density_kernel(const float* __restrict__ pts,
                                    float* __restrict__ penalty, int N) {
#pragma clang fp contract(off)
    const float R2 = (float)(0.4 * 0.4);  // matches JAX scalar promotion (0.16000001f)
    int b = blockIdx.y;
    int i = blockIdx.x * blockDim.x + threadIdx.x;
    const float* P = pts + (size_t)b * N * 3;

    __shared__ float sx[DENS_BLOCK], sy[DENS_BLOCK], sz[DENS_BLOCK];

    float px = 0.f, py = 0.f, pz = 0.f;
    if (i < N) {
        px = P[i * 3 + 0];
        py = P[i * 3 + 1];
        pz = P[i * 3 + 2];
    }

    int cnt = 0;
    for (int t0 = 0; t0 < N; t0 += DENS_BLOCK) {
        int j = t0 + threadIdx.x;
        __syncthreads();
        if (j < N) {
            sx[threadIdx.x] = P[j * 3 + 0];
            sy[threadIdx.x] = P[j * 3 + 1];
            sz[threadIdx.x] = P[j * 3 + 2];
        }
        __syncthreads();
        int lim = min(DENS_BLOCK, N - t0);
        for (int jj = 0; jj < lim; ++jj) {
            float dx = px - sx[jj];
            float dy = py - sy[jj];
            float dz = pz - sz[jj];
            float d2 = dx * dx;      // contract(off): match numpy's
            d2 = d2 + dy * dy;       // square-then-sum rounding order
            d2 = d2 + dz * dz;
            cnt += (d2 <= R2) ? 1 : 0;
        }
    }
    if (i < N) penalty[(size_t)b * N + i] = 1.0f / (float)cnt;
}

__global__ void __launch_bounds__(FPS_THREADS)
dfps_fps_kernel(const float* __restrict__ pts,
                const float* __restrict__ penalty,
                const int* __restrict__ npoint_p,
                int* __restrict__ out, int N) {
#pragma clang fp contract(off)
    const int b = blockIdx.x;
    const int tid = threadIdx.x;
    const int npoint = *npoint_p;
    const float* Pb = pts + (size_t)b * N * 3;
    const float* pen = penalty + (size_t)b * N;

    // Each thread owns FPS_P consecutive points, all state in registers.
    float x[FPS_P], y[FPS_P], z[FPS_P], md[FPS_P], pw[FPS_P];
    const int base = tid * FPS_P;
#pragma unroll
    for (int k = 0; k < FPS_P; ++k) {
        int idx = base + k;
        x[k] = Pb[idx * 3 + 0];
        y[k] = Pb[idx * 3 + 1];
        z[k] = Pb[idx * 3 + 2];
        md[k] = 1e10f;
        pw[k] = pen[idx];
    }

    __shared__ float scx, scy, scz;
    __shared__ float wv[FPS_THREADS / 64];
    __shared__ int   wi[FPS_THREADS / 64];

    int cur = 0;

    for (int t = 0; t < npoint; ++t) {
        if (tid == 0) out[(size_t)b * npoint + t] = cur;

        // Owner of `cur` broadcasts its coordinates.
        if (cur >= base && cur < base + FPS_P) {
            int k = cur - base;
            scx = x[k]; scy = y[k]; scz = z[k];
        }
        __syncthreads();  // barrier 1: scx ready; also fences prev-iter wv reads

        const float cx = scx, cy = scy, cz = scz;

        float bv = -1.0f;
        int   bi = 0;
#pragma unroll
        for (int k = 0; k < FPS_P; ++k) {
            // w = [1,1,2]: 1*|dx| + 1*|dy| + 2*|dz|, numpy add order
            float d = fabsf(x[k] - cx);
            d = d + fabsf(y[k] - cy);
            d = d + 2.0f * fabsf(z[k] - cz);
            float m = fminf(md[k], d);
            md[k] = m;
            float v = m * pw[k];
            // ascending k + strict '>' keeps first-occurrence argmax semantics
            if (v > bv) { bv = v; bi = base + k; }
        }

        // Wave64 (value,index) argmax reduce; ties -> smaller index.
        for (int off = 32; off > 0; off >>= 1) {
            float ov = __shfl_down(bv, off);
            int   oi = __shfl_down(bi, off);
            if (ov > bv || (ov == bv && oi < bi)) { bv = ov; bi = oi; }
        }
        if ((tid & 63) == 0) {
            wv[tid >> 6] = bv;
            wi[tid >> 6] = bi;
        }
        __syncthreads();  // barrier 2: wv ready

        // All threads redundantly reduce the per-wave results (wave w holds an
        // ascending index range, so strict '>' keeps the smallest index on tie).
        bv = wv[0]; bi = wi[0];
#pragma unroll
        for (int w = 1; w < FPS_THREADS / 64; ++w) {
            if (wv[w] > bv) { bv = wv[w]; bi = wi[w]; }
        }
        cur = bi;
        // no barrier needed here: barrier 1 of the next iteration fences
        // wv/wi reads before they are overwritten.
    }
}

extern "C" void kernel_launch(void* const* d_in, const int* in_sizes, int n_in,
                              void* d_out, int out_size, void* d_ws, size_t ws_size,
                              hipStream_t stream) {
    const float* points  = (const float*)d_in[0];
    const int*   npoint  = (const int*)d_in[2];
    int* out = (int*)d_out;

    const int B = 4;
    const int N = in_sizes[0] / (B * 3);  // 8192
    float* penalty = (float*)d_ws;        // B*N floats = 128 KiB

    dim3 dgrid(N / DENS_BLOCK, B);
    dfps_density_kernel<<<dgrid, DENS_BLOCK, 0, stream>>>(points, penalty, N);

    dfps_fps_kernel<<<B, FPS_THREADS, 0, stream>>>(points, penalty, npoint, out, N);
}

// Round 2
// 2458.184 us; speedup vs baseline: 1.4025x; 1.4025x over previous
//
#include <hip/hip_runtime.h>

// DFPS: density-weighted Manhattan furthest point sampling.
// points:   [B, N, 3] f32
// features: [B, C, N] f32 (unused)
// npoint:   int scalar (device, d_in[2])
// out:      [B, npoint] int32 indices

#define DENS_BLOCK 256
#define FPS_THREADS 512
#define FPS_P 16   // points per thread; FPS_THREADS * FPS_P == N (8192)
#define NWAVES (FPS_THREADS / 64)

__global__ void dfps_density_kernel(const float* __restrict__ pts,
                                    float* __restrict__ penalty, int N) {
#pragma clang fp contract(off)
    const float R2 = (float)(0.4 * 0.4);  // matches JAX scalar promotion
    int b = blockIdx.y;
    int i = blockIdx.x * blockDim.x + threadIdx.x;
    const float* P = pts + (size_t)b * N * 3;

    __shared__ float sx[DENS_BLOCK], sy[DENS_BLOCK], sz[DENS_BLOCK];

    float px = 0.f, py = 0.f, pz = 0.f;
    if (i < N) {
        px = P[i * 3 + 0];
        py = P[i * 3 + 1];
        pz = P[i * 3 + 2];
    }

    int cnt = 0;
    for (int t0 = 0; t0 < N; t0 += DENS_BLOCK) {
        int j = t0 + threadIdx.x;
        __syncthreads();
        if (j < N) {
            sx[threadIdx.x] = P[j * 3 + 0];
            sy[threadIdx.x] = P[j * 3 + 1];
            sz[threadIdx.x] = P[j * 3 + 2];
        }
        __syncthreads();
        int lim = min(DENS_BLOCK, N - t0);
        for (int jj = 0; jj < lim; ++jj) {
            float dx = px - sx[jj];
            float dy = py - sy[jj];
            float dz = pz - sz[jj];
            float d2 = dx * dx;      // contract(off): match numpy's
            d2 = d2 + dy * dy;       // square-then-sum rounding order
            d2 = d2 + dz * dz;
            cnt += (d2 <= R2) ? 1 : 0;
        }
    }
    if (i < N) penalty[(size_t)b * N + i] = 1.0f / (float)cnt;
}

__global__ void __launch_bounds__(FPS_THREADS, 2)
dfps_fps_kernel(const float* __restrict__ pts,
                const float* __restrict__ penalty,
                const int* __restrict__ npoint_p,
                int* __restrict__ out, int N) {
#pragma clang fp contract(off)
    const int b = blockIdx.x;
    const int tid = threadIdx.x;
    const int lane = tid & 63;
    const int w = tid >> 6;
    const int npoint = *npoint_p;
    const float* Pb = pts + (size_t)b * N * 3;
    const float* pen = penalty + (size_t)b * N;
    const int base = tid * FPS_P;
    // u64 key low word: N-1-idx  (larger lo <=> smaller idx -> first-match ties)
    const unsigned int L0 = (unsigned)(N - 1 - base);

    // Per-thread state, all in registers (~115 VGPR total, fits 256 budget).
    float x[FPS_P], y[FPS_P], z[FPS_P], md[FPS_P], pw[FPS_P];
#pragma unroll
    for (int k = 0; k < FPS_P; ++k) {
        int idx = base + k;
        x[k] = Pb[idx * 3 + 0];
        y[k] = Pb[idx * 3 + 1];
        z[k] = Pb[idx * 3 + 2];
        md[k] = 1e10f;
        pw[k] = pen[idx];
    }

    // Double-buffered per-wave winners: one barrier per iteration, no race
    // (reads of kbuf[p] at iter t sit between barrier_t and barrier_{t+1};
    //  next write to kbuf[p] happens only after barrier_{t+1}).
    __shared__ unsigned long long kbuf[2][NWAVES];

    int cur = 0;
    float cx = Pb[0], cy = Pb[1], cz = Pb[2];

    for (int t = 0; t < npoint; ++t) {
        if (tid == 0) out[(size_t)b * npoint + t] = cur;

        // 4 independent max-chains (ILP), combined by a 2-level tree.
        unsigned long long ck0 = 0ull, ck1 = 0ull, ck2 = 0ull, ck3 = 0ull;
#pragma unroll
        for (int k = 0; k < FPS_P; ++k) {
            // w=[1,1,2]; fmaf(2,|dz|,s) == s + 2*|dz| bitwise (2*|dz| exact)
            float d = fabsf(x[k] - cx) + fabsf(y[k] - cy);
            d = fmaf(2.0f, fabsf(z[k] - cz), d);
            float m = fminf(md[k], d);
            md[k] = m;
            float v = m * pw[k];  // v >= 0 -> float bits order == uint order
            unsigned long long key =
                ((unsigned long long)__float_as_uint(v) << 32) |
                (unsigned long long)(L0 - (unsigned)k);
            if ((k & 3) == 0) { if (key > ck0) ck0 = key; }
            else if ((k & 3) == 1) { if (key > ck1) ck1 = key; }
            else if ((k & 3) == 2) { if (key > ck2) ck2 = key; }
            else { if (key > ck3) ck3 = key; }
        }
        unsigned long long ka = ck0 > ck1 ? ck0 : ck1;
        unsigned long long kb = ck2 > ck3 ? ck2 : ck3;
        unsigned long long best = ka > kb ? ka : kb;

        // Wave64 u64 max reduce.
#pragma unroll
        for (int off = 32; off > 0; off >>= 1) {
            unsigned long long o = __shfl_down(best, off);
            if (o > best) best = o;
        }
        if (lane == 0) kbuf[t & 1][w] = best;
        __syncthreads();  // the single barrier per iteration

        // Redundant cross-wave reduce in every thread (residual partials are
        // <= their wave's winner, which is present in kbuf -> result uniform).
#pragma unroll
        for (int ww = 0; ww < NWAVES; ++ww) {
            unsigned long long o = kbuf[t & 1][ww];
            if (o > best) best = o;
        }
        cur = (N - 1) - (int)(unsigned)(best & 0xFFFFFFFFull);
        cur = __builtin_amdgcn_readfirstlane(cur);  // uniform -> scalar loads
        cx = Pb[cur * 3 + 0];
        cy = Pb[cur * 3 + 1];
        cz = Pb[cur * 3 + 2];
    }
}

extern "C" void kernel_launch(void* const* d_in, const int* in_sizes, int n_in,
                              void* d_out, int out_size, void* d_ws, size_t ws_size,
                              hipStream_t stream) {
    const float* points  = (const float*)d_in[0];
    const int*   npoint  = (const int*)d_in[2];
    int* out = (int*)d_out;

    const int B = 4;
    const int N = in_sizes[0] / (B * 3);  // 8192
    float* penalty = (float*)d_ws;        // B*N floats = 128 KiB

    dim3 dgrid(N / DENS_BLOCK, B);
    dfps_density_kernel<<<dgrid, DENS_BLOCK, 0, stream>>>(points, penalty, N);

    dfps_fps_kernel<<<B, FPS_THREADS, 0, stream>>>(points, penalty, npoint, out, N);
}

// Round 3
// 2030.486 us; speedup vs baseline: 1.6979x; 1.2106x over previous
//
#include <hip/hip_runtime.h>

// DFPS: density-weighted Manhattan furthest point sampling.
// points:   [B, N, 3] f32   (B=4, N=8192 fixed by the problem)
// features: [B, C, N] f32   (unused)
// npoint:   int scalar (device, d_in[2])
// out:      [B, npoint] int32 indices

#define NPTS 8192
#define DENS_BLOCK 256
#define DENS_SPLIT 2
#define FPS_THREADS 512
#define FPS_P 16   // FPS_THREADS * FPS_P == NPTS
#define NWAVES (FPS_THREADS / 64)

// ---------------- density ----------------

__global__ void dfps_density_partial(const float* __restrict__ pts,
                                     float* __restrict__ pen, int N) {
#pragma clang fp contract(off)
    const float R2 = (float)(0.4 * 0.4);  // matches JAX scalar promotion
    const int b = blockIdx.y;
    const int z = blockIdx.z;
    const int i = blockIdx.x * blockDim.x + threadIdx.x;
    const float* P = pts + (size_t)b * N * 3;

    __shared__ float4 tile[DENS_BLOCK];

    const float px = P[i * 3 + 0], py = P[i * 3 + 1], pz = P[i * 3 + 2];
    const int half = N / DENS_SPLIT;
    const int j0 = z * half;

    int cnt = 0;
    for (int t0 = j0; t0 < j0 + half; t0 += DENS_BLOCK) {
        int j = t0 + threadIdx.x;
        __syncthreads();
        tile[threadIdx.x] = make_float4(P[j * 3 + 0], P[j * 3 + 1], P[j * 3 + 2], 0.f);
        __syncthreads();
        for (int jj = 0; jj < DENS_BLOCK; ++jj) {
            float4 q = tile[jj];
            float dx = px - q.x, dy = py - q.y, dz = pz - q.z;
            float d2 = dx * dx;      // contract(off): numpy rounding order
            d2 = d2 + dy * dy;
            d2 = d2 + dz * dz;
            cnt += (d2 <= R2) ? 1 : 0;
        }
    }
    // counts are small ints -> float add exact & order-independent
    atomicAdd(&pen[(size_t)b * N + i], (float)cnt);
}

__global__ void dfps_finalize(float* pen, int total) {
    int i = blockIdx.x * blockDim.x + threadIdx.x;
    if (i < total) pen[i] = 1.0f / pen[i];
}

// ---------------- FPS ----------------

// u64 max across the 64-lane wave via DPP (VALU pipe, no LDS round-trips).
// Result valid in lane 63; masked-off rows keep stale values (unused).
#define DPP_STEP(ctrl, rmask)                                                   \
    {                                                                           \
        unsigned int nlo = (unsigned int)__builtin_amdgcn_update_dpp(           \
            0, (int)klo, (ctrl), (rmask), 0xF, false);                          \
        unsigned int nhi = (unsigned int)__builtin_amdgcn_update_dpp(           \
            0, (int)khi, (ctrl), (rmask), 0xF, false);                          \
        unsigned long long o = ((unsigned long long)nhi << 32) | nlo;           \
        unsigned long long c = ((unsigned long long)khi << 32) | klo;           \
        if (o > c) { klo = nlo; khi = nhi; }                                    \
    }

__global__ void __launch_bounds__(FPS_THREADS, 1)
dfps_fps_kernel(const float* __restrict__ pts,
                const float* __restrict__ penalty,
                const int* __restrict__ npoint_p,
                int* __restrict__ out, int N) {
#pragma clang fp contract(off)
    const int b = blockIdx.x;
    const int tid = threadIdx.x;
    const int lane = tid & 63;
    const int w = tid >> 6;
    const int npoint = *npoint_p;
    const float* Pb = pts + (size_t)b * N * 3;
    const float* pen = penalty + (size_t)b * N;
    const int base = tid * FPS_P;

    // Coordinate table in LDS (SoA planes) for low-latency winner broadcast.
    __shared__ float slx[NPTS], sly[NPTS], slz[NPTS];
    __shared__ unsigned long long kbuf[2][NWAVES];

    // Per-thread state in registers.
    float x[FPS_P], y[FPS_P], z[FPS_P], md[FPS_P], pw[FPS_P];
    unsigned int lo[FPS_P];  // hoisted key low words: N-1-idx (min-idx tiebreak)
#pragma unroll
    for (int k = 0; k < FPS_P; ++k) {
        int idx = base + k;
        x[k] = Pb[idx * 3 + 0];
        y[k] = Pb[idx * 3 + 1];
        z[k] = Pb[idx * 3 + 2];
        md[k] = 1e10f;
        pw[k] = pen[idx];
        lo[k] = (unsigned int)(N - 1 - idx);
        slx[idx] = x[k];
        sly[idx] = y[k];
        slz[idx] = z[k];
    }
    // First in-loop barrier (before any coord read) covers prefill visibility.

    int cur = 0;
    float cx = Pb[0], cy = Pb[1], cz = Pb[2];

    for (int t = 0; t < npoint; ++t) {
        if (tid == 0) out[(size_t)b * npoint + t] = cur;

        // Distance update + u64 argmax keys; 4 independent chains for ILP.
        unsigned long long ck0 = 0ull, ck1 = 0ull, ck2 = 0ull, ck3 = 0ull;
#pragma unroll
        for (int k = 0; k < FPS_P; ++k) {
            // w=[1,1,2]; fmaf(2,|dz|,s) == s + 2*|dz| bitwise (2*|dz| exact)
            float d = fabsf(x[k] - cx) + fabsf(y[k] - cy);
            d = fmaf(2.0f, fabsf(z[k] - cz), d);
            float m = fminf(md[k], d);
            md[k] = m;
            float v = m * pw[k];  // v >= 0 -> float bits order == uint order
            unsigned long long key =
                ((unsigned long long)__float_as_uint(v) << 32) | lo[k];
            if ((k & 3) == 0)      { if (key > ck0) ck0 = key; }
            else if ((k & 3) == 1) { if (key > ck1) ck1 = key; }
            else if ((k & 3) == 2) { if (key > ck2) ck2 = key; }
            else                   { if (key > ck3) ck3 = key; }
        }
        unsigned long long ka = ck0 > ck1 ? ck0 : ck1;
        unsigned long long kb = ck2 > ck3 ? ck2 : ck3;
        unsigned long long best = ka > kb ? ka : kb;

        // Wave64 u64 max via DPP: row_shr 1/2/4/8, then row_bcast 15/31.
        unsigned int klo = (unsigned int)best;
        unsigned int khi = (unsigned int)(best >> 32);
        DPP_STEP(0x111, 0xF)  // row_shr:1
        DPP_STEP(0x112, 0xF)  // row_shr:2
        DPP_STEP(0x114, 0xF)  // row_shr:4
        DPP_STEP(0x118, 0xF)  // row_shr:8
        DPP_STEP(0x142, 0xA)  // row_bcast:15 -> rows 1,3
        DPP_STEP(0x143, 0xC)  // row_bcast:31 -> rows 2,3
        unsigned int wlo = (unsigned int)__builtin_amdgcn_readlane((int)klo, 63);
        unsigned int whi = (unsigned int)__builtin_amdgcn_readlane((int)khi, 63);

        if (lane == 0)
            kbuf[t & 1][w] = ((unsigned long long)whi << 32) | wlo;
        __syncthreads();  // single barrier per iteration (double-buffered kbuf)

        // Redundant cross-wave reduce in every thread -> uniform result.
        unsigned long long b0 = kbuf[t & 1][0], b1 = kbuf[t & 1][1];
        unsigned long long b2 = kbuf[t & 1][2], b3 = kbuf[t & 1][3];
        unsigned long long b4 = kbuf[t & 1][4], b5 = kbuf[t & 1][5];
        unsigned long long b6 = kbuf[t & 1][6], b7 = kbuf[t & 1][7];
        b0 = b0 > b1 ? b0 : b1;
        b2 = b2 > b3 ? b2 : b3;
        b4 = b4 > b5 ? b4 : b5;
        b6 = b6 > b7 ? b6 : b7;
        b0 = b0 > b2 ? b0 : b2;
        b4 = b4 > b6 ? b4 : b6;
        b0 = b0 > b4 ? b0 : b4;

        cur = (N - 1) - (int)(unsigned int)(b0 & 0xFFFFFFFFull);
        // Winner coords from LDS (uniform address -> broadcast read).
        cx = slx[cur];
        cy = sly[cur];
        cz = slz[cur];
    }
}

extern "C" void kernel_launch(void* const* d_in, const int* in_sizes, int n_in,
                              void* d_out, int out_size, void* d_ws, size_t ws_size,
                              hipStream_t stream) {
    const float* points  = (const float*)d_in[0];
    const int*   npoint  = (const int*)d_in[2];
    int* out = (int*)d_out;

    const int B = 4;
    const int N = in_sizes[0] / (B * 3);  // 8192
    float* penalty = (float*)d_ws;        // B*N floats = 128 KiB

    hipMemsetAsync(penalty, 0, (size_t)B * N * sizeof(float), stream);

    dim3 dgrid(N / DENS_BLOCK, B, DENS_SPLIT);
    dfps_density_partial<<<dgrid, DENS_BLOCK, 0, stream>>>(points, penalty, N);
    dfps_finalize<<<(B * N + 255) / 256, 256, 0, stream>>>(penalty, B * N);

    dfps_fps_kernel<<<B, FPS_THREADS, 0, stream>>>(points, penalty, npoint, out, N);
}